// Round 4
// baseline (1117.695 us; speedup 1.0000x reference)
//
#include <hip/hip_runtime.h>

// HGCN on MI355X. logmap0(expmap0(v)) == v for all vectors occurring here,
// so the model reduces to:
//   h1 = feat@W1+b1; t1 = sigmoid(segmean(h1))
//   h2 = t1@W2+b2;   t2 = sigmoid(segmean(h2))
//   out = relu(t2@W3+b3)@W4 + b4
// R1: fp32 atomicAdd scatter = atomic wall -> counting-sort CSR + gather.
// R2: single-block scan = latency wall -> hierarchical scan.
// R3: 4B random scatter in bucket_k write-allocates 64B lines (WRITE_SIZE
//     105MB for a 6.4MB payload) -> two-level radix: coarse 128-node buckets
//     (line-dense appends), then per-bucket LDS counting sort (coalesced out).

constexpr int BSHIFT = 7;              // 128 nodes per coarse bucket
constexpr int BNODES = 1 << BSHIFT;

__device__ __forceinline__ float sigmoidf(float x) {
    return 1.0f / (1.0f + __expf(-x));
}

// ---------------- CSR build ----------------

// Pass A: coarse histogram over dst>>BSHIFT
__global__ __launch_bounds__(256) void hist_c(const int* __restrict__ dst,
                                              int* __restrict__ chist, int E) {
    int e = blockIdx.x * 256 + threadIdx.x;
    if (e < E) atomicAdd(chist + (dst[e] >> BSHIFT), 1);
}

// Pass B: single-block scan of NBUCK (<1024) coarse counters.
__global__ __launch_bounds__(1024) void scanc_k(const int* __restrict__ chist,
                                                int* __restrict__ coff,
                                                int* __restrict__ ccur,
                                                int* __restrict__ offN,
                                                int NBUCK, int E) {
    __shared__ int sh[1024];
    const int tid = threadIdx.x;
    sh[tid] = (tid < NBUCK) ? chist[tid] : 0;
    __syncthreads();
    for (int d = 1; d < 1024; d <<= 1) {
        int v = 0;
        if (tid >= d) v = sh[tid - d];
        __syncthreads();
        if (tid >= d) sh[tid] += v;
        __syncthreads();
    }
    if (tid < NBUCK) {
        int ex = (tid > 0) ? sh[tid - 1] : 0;
        coff[tid] = ex;
        ccur[tid] = ex;
    }
    if (tid == 0) { coff[NBUCK] = E; *offN = E; }
}

// Pass C: append (src,dst) pairs into coarse-bucket regions (line-dense).
__global__ __launch_bounds__(256) void bucket_c(const int* __restrict__ src,
                                                const int* __restrict__ dst,
                                                int* __restrict__ ccur,
                                                int2* __restrict__ pe, int E) {
    int e = blockIdx.x * 256 + threadIdx.x;
    if (e >= E) return;
    int s = src[e], d = dst[e];
    int pos = atomicAdd(ccur + (d >> BSHIFT), 1);
    pe[pos] = make_int2(s, d);
}

// Pass D: one block per coarse bucket; LDS counting sort of ~2K edges over
// 128 nodes. Emits per-node off[] and coalesced ssrc[].
__global__ __launch_bounds__(256) void csr_fine(const int2* __restrict__ pe,
                                                const int* __restrict__ coff,
                                                int* __restrict__ off,
                                                int* __restrict__ ssrc, int N) {
    __shared__ int cnt[BNODES];   // counts -> inclusive scan
    __shared__ int cur[BNODES];   // placement cursors (exclusive offsets)
    const int b = blockIdx.x;
    const int node0 = b << BSHIFT;
    const int nn = min(BNODES, N - node0);
    const int cbeg = coff[b], cend = coff[b + 1];
    const int tid = threadIdx.x;

    if (tid < BNODES) cnt[tid] = 0;
    __syncthreads();
    for (int i = cbeg + tid; i < cend; i += 256)
        atomicAdd(&cnt[pe[i].y - node0], 1);
    __syncthreads();
    // inclusive Hillis-Steele over 128 entries
    #pragma unroll
    for (int d = 1; d < BNODES; d <<= 1) {
        int v = 0;
        if (tid >= d && tid < BNODES) v = cnt[tid - d];
        __syncthreads();
        if (tid >= d && tid < BNODES) cnt[tid] += v;
        __syncthreads();
    }
    if (tid < nn) {
        int ex = (tid > 0) ? cnt[tid - 1] : 0;
        off[node0 + tid] = cbeg + ex;
        cur[tid] = ex;
    }
    __syncthreads();
    for (int i = cbeg + tid; i < cend; i += 256) {
        int2 p = pe[i];                      // L2-hot re-read
        int pos = cbeg + atomicAdd(&cur[p.y - node0], 1);
        ssrc[pos] = p.x;
    }
}

// ---------------- aggregation (gather) ----------------
// 16 lanes per node, each lane owns 4 consecutive floats of the 64-dim row.
__global__ __launch_bounds__(256) void agg_k(const float* __restrict__ h,
                                             const int* __restrict__ off,
                                             const int* __restrict__ ssrc,
                                             float* __restrict__ out, int N) {
    int t = blockIdx.x * 256 + threadIdx.x;
    int g = t >> 4;
    if (g >= N) return;
    int q = (t & 15) << 2;
    int beg = off[g], end = off[g + 1];
    float4 acc = make_float4(0.f, 0.f, 0.f, 0.f);
    for (int i = beg; i < end; i++) {
        int s = ssrc[i];
        float4 v = *(const float4*)(h + (size_t)s * 64 + q);
        acc.x += v.x; acc.y += v.y; acc.z += v.z; acc.w += v.w;
    }
    float inv = 1.0f / (float)max(end - beg, 1);
    float4 o;
    o.x = sigmoidf(acc.x * inv);
    o.y = sigmoidf(acc.y * inv);
    o.z = sigmoidf(acc.z * inv);
    o.w = sigmoidf(acc.w * inv);
    *(float4*)(out + (size_t)g * 64 + q) = o;
}

// ---------------- tiled fp32 GEMM ----------------
template<int K, int NCP, int NCR, int TR, int TC, bool RELU>
__global__ __launch_bounds__(256) void gemm_t(
    const float* __restrict__ in, const float* __restrict__ W,
    const float* __restrict__ bias, float* __restrict__ out, int N)
{
    constexpr int TX   = NCP / TC;
    constexpr int TY   = 256 / TX;
    constexpr int ROWS = TY * TR;
    constexpr int TSTR = ROWS + 1;

    __shared__ alignas(16) float Ws[K * NCP];
    __shared__ alignas(16) float Ts[K * TSTR];
    __shared__ float bs[NCP];

    const int tid = threadIdx.x;

    if constexpr (NCP == NCR) {
        constexpr int NW4 = K * NCP / 4;
        const float4* Wg = (const float4*)W;
        float4* Wl = (float4*)Ws;
        #pragma unroll
        for (int i = 0; i < NW4 / 256; i++) Wl[tid + 256 * i] = Wg[tid + 256 * i];
    } else {
        for (int i = tid; i < K * NCP; i += 256) {
            int k = i / NCP, c = i - k * NCP;
            Ws[i] = (c < NCR) ? W[k * NCR + c] : 0.0f;
        }
    }
    for (int i = tid; i < NCP; i += 256) bs[i] = (i < NCR) ? bias[i] : 0.0f;

    const int row0 = blockIdx.x * ROWS;
    constexpr int KC4 = K / 4;
    constexpr int NT4 = ROWS * KC4;
    for (int i = tid; i < NT4; i += 256) {
        int r  = i / KC4;
        int c4 = (i - r * KC4) * 4;
        int row = row0 + r;
        float4 v = make_float4(0.f, 0.f, 0.f, 0.f);
        if (row < N) v = *(const float4*)(in + (size_t)row * K + c4);
        Ts[(c4 + 0) * TSTR + r] = v.x;
        Ts[(c4 + 1) * TSTR + r] = v.y;
        Ts[(c4 + 2) * TSTR + r] = v.z;
        Ts[(c4 + 3) * TSTR + r] = v.w;
    }
    __syncthreads();

    const int tx = tid % TX, ty = tid / TX;
    const int colb = tx * TC, rowb = ty * TR;
    float acc[TR][TC];
    #pragma unroll
    for (int i = 0; i < TR; i++)
        #pragma unroll
        for (int j = 0; j < TC; j++) acc[i][j] = bs[colb + j];

    for (int k = 0; k < K; k++) {
        float tv[TR];
        #pragma unroll
        for (int i = 0; i < TR; i++) tv[i] = Ts[k * TSTR + rowb + i];
        #pragma unroll
        for (int j = 0; j < TC; j++) {
            float wv = Ws[k * NCP + colb + j];
            #pragma unroll
            for (int i = 0; i < TR; i++) acc[i][j] = fmaf(tv[i], wv, acc[i][j]);
        }
    }

    #pragma unroll
    for (int i = 0; i < TR; i++) {
        int row = row0 + rowb + i;
        if (row < N) {
            #pragma unroll
            for (int j = 0; j < TC; j++) {
                int c = colb + j;
                if (c < NCR) {
                    float v = acc[i][j];
                    if (RELU) v = fmaxf(v, 0.f);
                    out[(size_t)row * NCR + c] = v;
                }
            }
        }
    }
}

extern "C" void kernel_launch(void* const* d_in, const int* in_sizes, int n_in,
                              void* d_out, int out_size, void* d_ws, size_t ws_size,
                              hipStream_t stream)
{
    const float* feat = (const float*)d_in[0];
    const int*   eidx = (const int*)d_in[1];
    const float* W1 = (const float*)d_in[2];
    const float* b1 = (const float*)d_in[3];
    const float* W2 = (const float*)d_in[4];
    const float* b2 = (const float*)d_in[5];
    const float* W3 = (const float*)d_in[6];
    const float* b3 = (const float*)d_in[7];
    const float* W4 = (const float*)d_in[8];
    const float* b4 = (const float*)d_in[9];

    const int N = in_sizes[0] / 64;
    const int E = in_sizes[1] / 2;
    const int* src = eidx;
    const int* dst = eidx + E;

    const int NBUCK = (N + BNODES - 1) / BNODES;   // 782 for N=100000

    float* A     = (float*)d_ws;                 // N*64  agg / t buffer
    float* B     = A  + (size_t)N * 64;          // N*64  h buffer
    float* H3    = B  + (size_t)N * 64;          // N*128 MLP hidden
    int*   off   = (int*)(H3 + (size_t)N * 128); // N+1
    int*   chist = off + (N + 1);                // NBUCK
    int*   coff  = chist + NBUCK;                // NBUCK+1
    int*   ccur  = coff + (NBUCK + 1);           // NBUCK
    // pe & ssrc alias the H3 region (H3 is dead until gemm3, CSR dead after agg2)
    int*   ssrc  = (int*)H3;                     // E ints   (6.4 MB)
    int2*  pe    = (int2*)(ssrc + E);            // E int2   (12.8 MB)
    float* out   = (float*)d_out;

    hipMemsetAsync(chist, 0, (size_t)NBUCK * sizeof(int), stream);

    const dim3 blk(256);
    const int gE  = (E + 255) / 256;
    const int g64 = (N + 63) / 64;
    const int g32 = (N + 31) / 32;
    const int gAg = (int)(((size_t)N * 16 + 255) / 256);

    // CSR build (used by both aggregation rounds)
    hist_c<<<gE, blk, 0, stream>>>(dst, chist, E);
    scanc_k<<<1, dim3(1024), 0, stream>>>(chist, coff, ccur, off + N, NBUCK, E);
    bucket_c<<<gE, blk, 0, stream>>>(src, dst, ccur, pe, E);
    csr_fine<<<NBUCK, blk, 0, stream>>>(pe, coff, off, ssrc, N);

    // h1 = feat@W1+b1
    gemm_t<64, 64, 64, 4, 4, false><<<g64, blk, 0, stream>>>(feat, W1, b1, B, N);
    // t1 = sigmoid(mean h1[src])
    agg_k<<<gAg, blk, 0, stream>>>(B, off, ssrc, A, N);
    // h2 = t1@W2+b2
    gemm_t<64, 64, 64, 4, 4, false><<<g64, blk, 0, stream>>>(A, W2, b2, B, N);
    // t2 = sigmoid(mean h2[src])
    agg_k<<<gAg, blk, 0, stream>>>(B, off, ssrc, A, N);
    // h3 = relu(t2@W3+b3)  [N,128]
    gemm_t<64, 128, 128, 4, 8, true><<<g64, blk, 0, stream>>>(A, W3, b3, H3, N);
    // out = h3@W4+b4       [N,40]
    gemm_t<128, 64, 40, 2, 4, false><<<g32, blk, 0, stream>>>(H3, W4, b4, out, N);
}

// Round 5
// 405.203 us; speedup vs baseline: 2.7584x; 2.7584x over previous
//
#include <hip/hip_runtime.h>

// HGCN on MI355X. logmap0(expmap0(v)) == v for all vectors occurring here,
// so the model reduces to:
//   h1 = feat@W1+b1; t1 = sigmoid(segmean(h1))
//   h2 = t1@W2+b2;   t2 = sigmoid(segmean(h2))
//   out = relu(t2@W3+b3)@W4 + b4
// R1: fp32 atomicAdd scatter = atomic wall -> counting-sort CSR + gather.
// R2: single-block scan = latency wall -> hierarchical scan.
// R3: 4B random scatter write-allocates 64B lines -> coarse buckets.
// R4 FAIL: per-edge global atomicAdd on 782 counters = contention wall
//     (376us, and hist_c likewise). Fix: radix-partition pass with per-block
//     LDS histogram + LDS staging + dense cooperative write-out; only ~196
//     global atomics per block.

constexpr int CSHIFT = 9;               // 512 nodes per coarse bucket
constexpr int CNODES = 1 << CSHIFT;
constexpr int EPB    = 4096;            // edges per partition block
constexpr int EPT    = EPB / 256;       // 16 edges per thread

__device__ __forceinline__ float sigmoidf(float x) {
    return 1.0f / (1.0f + __expf(-x));
}

// ---------------- CSR build ----------------

// Pass A: coarse histogram, LDS-aggregated (1 global atomic per bucket per block)
__global__ __launch_bounds__(256) void hist_c(const int* __restrict__ dst,
                                              int* __restrict__ chist,
                                              int E, int NBUCK) {
    __shared__ int h[256];
    const int tid = threadIdx.x;
    h[tid] = 0;
    __syncthreads();
    const int e0 = blockIdx.x * EPB;
    const int ec = min(EPB, E - e0);
    for (int j = 0; j < EPT; j++) {
        int idx = tid + j * 256;
        if (idx < ec) atomicAdd(&h[dst[e0 + idx] >> CSHIFT], 1);
    }
    __syncthreads();
    if (tid < NBUCK && h[tid] > 0) atomicAdd(chist + tid, h[tid]);
}

// Pass B: single-block scan of NBUCK (<=256) coarse counters.
__global__ __launch_bounds__(256) void scanc_k(const int* __restrict__ chist,
                                               int* __restrict__ coff,
                                               int* __restrict__ ccur,
                                               int* __restrict__ offN,
                                               int NBUCK, int E) {
    __shared__ int sh[256];
    const int tid = threadIdx.x;
    sh[tid] = (tid < NBUCK) ? chist[tid] : 0;
    __syncthreads();
    for (int d = 1; d < 256; d <<= 1) {
        int v = 0;
        if (tid >= d) v = sh[tid - d];
        __syncthreads();
        if (tid >= d) sh[tid] += v;
        __syncthreads();
    }
    if (tid < NBUCK) {
        int ex = (tid > 0) ? sh[tid - 1] : 0;
        coff[tid] = ex;
        ccur[tid] = ex;
    }
    if (tid == 0) { coff[NBUCK] = E; *offN = E; }
}

// Pass C: radix-partition pass. Per-block: LDS hist -> scan -> reserve global
// space (196 atomics) -> reorder pairs by bucket in LDS staging -> dense
// cooperative write-out (lanes write consecutive staging entries; runs avg
// ~21 pairs = 167B, near line-dense).
__global__ __launch_bounds__(256) void part_k(const int* __restrict__ src,
                                              const int* __restrict__ dst,
                                              int* __restrict__ ccur,
                                              int2* __restrict__ pe,
                                              int E, int NBUCK) {
    __shared__ int  hist[256];
    __shared__ int  exoff[256];
    __shared__ int  lcur[256];
    __shared__ int  gbase[256];
    __shared__ int2 stage[EPB];          // 32 KB

    const int tid = threadIdx.x;
    const int e0  = blockIdx.x * EPB;
    const int ec  = min(EPB, E - e0);

    int s[EPT], d[EPT], bk[EPT];
    hist[tid] = 0;
    __syncthreads();
    #pragma unroll
    for (int j = 0; j < EPT; j++) {
        int idx = tid + j * 256;
        if (idx < ec) {
            s[j]  = src[e0 + idx];
            d[j]  = dst[e0 + idx];
            bk[j] = d[j] >> CSHIFT;
            atomicAdd(&hist[bk[j]], 1);
        } else bk[j] = -1;
    }
    __syncthreads();
    const int h = hist[tid];
    // inclusive scan of hist (reuse exoff as scan buffer)
    exoff[tid] = h;
    __syncthreads();
    for (int dd = 1; dd < 256; dd <<= 1) {
        int v = 0;
        if (tid >= dd) v = exoff[tid - dd];
        __syncthreads();
        if (tid >= dd) exoff[tid] += v;
        __syncthreads();
    }
    const int incl = exoff[tid];
    const int ex   = incl - h;
    int gb = 0;
    if (tid < NBUCK && h > 0) gb = atomicAdd(ccur + tid, h);
    __syncthreads();
    exoff[tid] = ex;      // final: bucket run start in staging
    lcur[tid]  = ex;
    gbase[tid] = gb;
    __syncthreads();
    #pragma unroll
    for (int j = 0; j < EPT; j++) {
        if (bk[j] >= 0) {
            int l = atomicAdd(&lcur[bk[j]], 1);
            stage[l] = make_int2(s[j], d[j]);
        }
    }
    __syncthreads();
    for (int i = tid; i < ec; i += 256) {
        int2 p = stage[i];
        int b = p.y >> CSHIFT;
        pe[gbase[b] + (i - exoff[b])] = p;
    }
}

// Pass D: one block per coarse bucket; LDS counting sort of ~8K edges over
// 512 nodes. Emits per-node off[] and coalesced ssrc[].
__global__ __launch_bounds__(256) void csr_fine(const int2* __restrict__ pe,
                                                const int* __restrict__ coff,
                                                int* __restrict__ off,
                                                int* __restrict__ ssrc, int N) {
    __shared__ int cnt[CNODES];
    __shared__ int cur[CNODES];
    __shared__ int part[256];
    const int b = blockIdx.x;
    const int node0 = b << CSHIFT;
    const int cbeg = coff[b], cend = coff[b + 1];
    const int tid = threadIdx.x;

    cnt[tid] = 0;
    cnt[tid + 256] = 0;
    __syncthreads();
    for (int i = cbeg + tid; i < cend; i += 256)
        atomicAdd(&cnt[pe[i].y - node0], 1);
    __syncthreads();
    // scan 512 entries: 2 per thread + 256-wide Hillis-Steele over partials
    const int c0 = cnt[2 * tid], c1 = cnt[2 * tid + 1];
    part[tid] = c0 + c1;
    __syncthreads();
    for (int d = 1; d < 256; d <<= 1) {
        int v = 0;
        if (tid >= d) v = part[tid - d];
        __syncthreads();
        if (tid >= d) part[tid] += v;
        __syncthreads();
    }
    const int ex = (tid > 0) ? part[tid - 1] : 0;
    cnt[2 * tid]     = ex;        // each thread rewrites only its own entries
    cnt[2 * tid + 1] = ex + c0;
    cur[2 * tid]     = ex;
    cur[2 * tid + 1] = ex + c0;
    if (node0 + 2 * tid     < N) off[node0 + 2 * tid]     = cbeg + ex;
    if (node0 + 2 * tid + 1 < N) off[node0 + 2 * tid + 1] = cbeg + ex + c0;
    __syncthreads();
    for (int i = cbeg + tid; i < cend; i += 256) {
        int2 p = pe[i];
        int pos = cbeg + atomicAdd(&cur[p.y - node0], 1);
        ssrc[pos] = p.x;
    }
}

// ---------------- aggregation (gather) ----------------
// 16 lanes per node, each lane owns 4 consecutive floats of the 64-dim row.
__global__ __launch_bounds__(256) void agg_k(const float* __restrict__ h,
                                             const int* __restrict__ off,
                                             const int* __restrict__ ssrc,
                                             float* __restrict__ out, int N) {
    int t = blockIdx.x * 256 + threadIdx.x;
    int g = t >> 4;
    if (g >= N) return;
    int q = (t & 15) << 2;
    int beg = off[g], end = off[g + 1];
    float4 acc = make_float4(0.f, 0.f, 0.f, 0.f);
    for (int i = beg; i < end; i++) {
        int s = ssrc[i];
        float4 v = *(const float4*)(h + (size_t)s * 64 + q);
        acc.x += v.x; acc.y += v.y; acc.z += v.z; acc.w += v.w;
    }
    float inv = 1.0f / (float)max(end - beg, 1);
    float4 o;
    o.x = sigmoidf(acc.x * inv);
    o.y = sigmoidf(acc.y * inv);
    o.z = sigmoidf(acc.z * inv);
    o.w = sigmoidf(acc.w * inv);
    *(float4*)(out + (size_t)g * 64 + q) = o;
}

// ---------------- tiled fp32 GEMM ----------------
template<int K, int NCP, int NCR, int TR, int TC, bool RELU>
__global__ __launch_bounds__(256) void gemm_t(
    const float* __restrict__ in, const float* __restrict__ W,
    const float* __restrict__ bias, float* __restrict__ out, int N)
{
    constexpr int TX   = NCP / TC;
    constexpr int TY   = 256 / TX;
    constexpr int ROWS = TY * TR;
    constexpr int TSTR = ROWS + 1;

    __shared__ alignas(16) float Ws[K * NCP];
    __shared__ alignas(16) float Ts[K * TSTR];
    __shared__ float bs[NCP];

    const int tid = threadIdx.x;

    if constexpr (NCP == NCR) {
        constexpr int NW4 = K * NCP / 4;
        const float4* Wg = (const float4*)W;
        float4* Wl = (float4*)Ws;
        #pragma unroll
        for (int i = 0; i < NW4 / 256; i++) Wl[tid + 256 * i] = Wg[tid + 256 * i];
    } else {
        for (int i = tid; i < K * NCP; i += 256) {
            int k = i / NCP, c = i - k * NCP;
            Ws[i] = (c < NCR) ? W[k * NCR + c] : 0.0f;
        }
    }
    for (int i = tid; i < NCP; i += 256) bs[i] = (i < NCR) ? bias[i] : 0.0f;

    const int row0 = blockIdx.x * ROWS;
    constexpr int KC4 = K / 4;
    constexpr int NT4 = ROWS * KC4;
    for (int i = tid; i < NT4; i += 256) {
        int r  = i / KC4;
        int c4 = (i - r * KC4) * 4;
        int row = row0 + r;
        float4 v = make_float4(0.f, 0.f, 0.f, 0.f);
        if (row < N) v = *(const float4*)(in + (size_t)row * K + c4);
        Ts[(c4 + 0) * TSTR + r] = v.x;
        Ts[(c4 + 1) * TSTR + r] = v.y;
        Ts[(c4 + 2) * TSTR + r] = v.z;
        Ts[(c4 + 3) * TSTR + r] = v.w;
    }
    __syncthreads();

    const int tx = tid % TX, ty = tid / TX;
    const int colb = tx * TC, rowb = ty * TR;
    float acc[TR][TC];
    #pragma unroll
    for (int i = 0; i < TR; i++)
        #pragma unroll
        for (int j = 0; j < TC; j++) acc[i][j] = bs[colb + j];

    for (int k = 0; k < K; k++) {
        float tv[TR];
        #pragma unroll
        for (int i = 0; i < TR; i++) tv[i] = Ts[k * TSTR + rowb + i];
        #pragma unroll
        for (int j = 0; j < TC; j++) {
            float wv = Ws[k * NCP + colb + j];
            #pragma unroll
            for (int i = 0; i < TR; i++) acc[i][j] = fmaf(tv[i], wv, acc[i][j]);
        }
    }

    #pragma unroll
    for (int i = 0; i < TR; i++) {
        int row = row0 + rowb + i;
        if (row < N) {
            #pragma unroll
            for (int j = 0; j < TC; j++) {
                int c = colb + j;
                if (c < NCR) {
                    float v = acc[i][j];
                    if (RELU) v = fmaxf(v, 0.f);
                    out[(size_t)row * NCR + c] = v;
                }
            }
        }
    }
}

extern "C" void kernel_launch(void* const* d_in, const int* in_sizes, int n_in,
                              void* d_out, int out_size, void* d_ws, size_t ws_size,
                              hipStream_t stream)
{
    const float* feat = (const float*)d_in[0];
    const int*   eidx = (const int*)d_in[1];
    const float* W1 = (const float*)d_in[2];
    const float* b1 = (const float*)d_in[3];
    const float* W2 = (const float*)d_in[4];
    const float* b2 = (const float*)d_in[5];
    const float* W3 = (const float*)d_in[6];
    const float* b3 = (const float*)d_in[7];
    const float* W4 = (const float*)d_in[8];
    const float* b4 = (const float*)d_in[9];

    const int N = in_sizes[0] / 64;
    const int E = in_sizes[1] / 2;
    const int* src = eidx;
    const int* dst = eidx + E;

    const int NBUCK = (N + CNODES - 1) / CNODES;   // 196 for N=100000

    float* A     = (float*)d_ws;                 // N*64  agg / t buffer
    float* B     = A  + (size_t)N * 64;          // N*64  h buffer
    float* H3    = B  + (size_t)N * 64;          // N*128 MLP hidden
    int*   off   = (int*)(H3 + (size_t)N * 128); // N+1
    int*   chist = off + (N + 1);                // NBUCK
    int*   coff  = chist + NBUCK;                // NBUCK+1
    int*   ccur  = coff + (NBUCK + 1);           // NBUCK
    // pe & ssrc alias the H3 region (H3 dead until gemm3, CSR dead after agg2)
    int*   ssrc  = (int*)H3;                     // E ints   (6.4 MB)
    int2*  pe    = (int2*)(ssrc + E);            // E int2   (12.8 MB)
    float* out   = (float*)d_out;

    hipMemsetAsync(chist, 0, (size_t)NBUCK * sizeof(int), stream);

    const dim3 blk(256);
    const int gP  = (E + EPB - 1) / EPB;   // 391
    const int g64 = (N + 63) / 64;
    const int g32 = (N + 31) / 32;
    const int gAg = (int)(((size_t)N * 16 + 255) / 256);

    // CSR build (used by both aggregation rounds)
    hist_c<<<gP, blk, 0, stream>>>(dst, chist, E, NBUCK);
    scanc_k<<<1, blk, 0, stream>>>(chist, coff, ccur, off + N, NBUCK, E);
    part_k<<<gP, blk, 0, stream>>>(src, dst, ccur, pe, E, NBUCK);
    csr_fine<<<NBUCK, blk, 0, stream>>>(pe, coff, off, ssrc, N);

    // h1 = feat@W1+b1
    gemm_t<64, 64, 64, 4, 4, false><<<g64, blk, 0, stream>>>(feat, W1, b1, B, N);
    // t1 = sigmoid(mean h1[src])
    agg_k<<<gAg, blk, 0, stream>>>(B, off, ssrc, A, N);
    // h2 = t1@W2+b2
    gemm_t<64, 64, 64, 4, 4, false><<<g64, blk, 0, stream>>>(A, W2, b2, B, N);
    // t2 = sigmoid(mean h2[src])
    agg_k<<<gAg, blk, 0, stream>>>(B, off, ssrc, A, N);
    // h3 = relu(t2@W3+b3)  [N,128]
    gemm_t<64, 128, 128, 4, 8, true><<<g64, blk, 0, stream>>>(A, W3, b3, H3, N);
    // out = h3@W4+b4       [N,40]
    gemm_t<128, 64, 40, 2, 4, false><<<g32, blk, 0, stream>>>(H3, W4, b4, out, N);
}

// Round 6
// 334.799 us; speedup vs baseline: 3.3384x; 1.2103x over previous
//
#include <hip/hip_runtime.h>

// HGCN on MI355X. logmap0(expmap0(v)) == v for all vectors occurring here,
// so the model reduces to:
//   h1 = feat@W1+b1; t1 = sigmoid(segmean(h1))
//   h2 = t1@W2+b2;   t2 = sigmoid(segmean(h2))
//   out = relu(t2@W3+b3)@W4 + b4
// R1: fp32 atomicAdd scatter = atomic wall -> counting-sort CSR + gather.
// R2: single-block scan = latency wall -> hierarchical scan.
// R3: 4B random scatter write-allocates 64B lines -> coarse buckets.
// R4: global atomics on few counters = contention wall -> per-block LDS
//     staging radix partition (part_k).
// R5: agg_k gather is byte-bound (FETCH 177MB vs 25.6MB h). R6: bf16 gather
//     rows (256->128B = 1 line), fuse gemm3+gemm4 (kill 102MB h3 roundtrip),
//     pack CSR pair into one int.

constexpr int CSHIFT = 9;               // 512 nodes per coarse bucket
constexpr int CNODES = 1 << CSHIFT;
constexpr int EPB    = 4096;            // edges per partition block
constexpr int EPT    = EPB / 256;

__device__ __forceinline__ float sigmoidf(float x) {
    return 1.0f / (1.0f + __expf(-x));
}
__device__ __forceinline__ unsigned short f2bf(float f) {   // RNE f32->bf16
    unsigned int u = __float_as_uint(f);
    u = (u + 0x7FFFu + ((u >> 16) & 1u)) >> 16;
    return (unsigned short)u;
}

// ---------------- CSR build ----------------

__global__ __launch_bounds__(256) void hist_c(const int* __restrict__ dst,
                                              int* __restrict__ chist,
                                              int E, int NBUCK) {
    __shared__ int h[256];
    const int tid = threadIdx.x;
    h[tid] = 0;
    __syncthreads();
    const int e0 = blockIdx.x * EPB;
    const int ec = min(EPB, E - e0);
    for (int j = 0; j < EPT; j++) {
        int idx = tid + j * 256;
        if (idx < ec) atomicAdd(&h[dst[e0 + idx] >> CSHIFT], 1);
    }
    __syncthreads();
    if (tid < NBUCK && h[tid] > 0) atomicAdd(chist + tid, h[tid]);
}

__global__ __launch_bounds__(256) void scanc_k(const int* __restrict__ chist,
                                               int* __restrict__ coff,
                                               int* __restrict__ ccur,
                                               int* __restrict__ offN,
                                               int NBUCK, int E) {
    __shared__ int sh[256];
    const int tid = threadIdx.x;
    sh[tid] = (tid < NBUCK) ? chist[tid] : 0;
    __syncthreads();
    for (int d = 1; d < 256; d <<= 1) {
        int v = 0;
        if (tid >= d) v = sh[tid - d];
        __syncthreads();
        if (tid >= d) sh[tid] += v;
        __syncthreads();
    }
    if (tid < NBUCK) {
        int ex = (tid > 0) ? sh[tid - 1] : 0;
        coff[tid] = ex;
        ccur[tid] = ex;
    }
    if (tid == 0) { coff[NBUCK] = E; *offN = E; }
}

// Radix partition: LDS hist -> scan -> reserve global space -> LDS staging
// reorder -> dense cooperative write-out of packed (src | localdst<<17) ints.
__global__ __launch_bounds__(256) void part_k(const int* __restrict__ src,
                                              const int* __restrict__ dst,
                                              int* __restrict__ ccur,
                                              int* __restrict__ pe,
                                              int E, int NBUCK) {
    __shared__ int  hist[256];
    __shared__ int  exoff[256];
    __shared__ int  lcur[256];
    __shared__ int  gbase[256];
    __shared__ int  stage[EPB];            // 16 KB
    __shared__ unsigned char stageB[EPB];  // 4 KB bucket ids

    const int tid = threadIdx.x;
    const int e0  = blockIdx.x * EPB;
    const int ec  = min(EPB, E - e0);

    int pk[EPT], bk[EPT];
    hist[tid] = 0;
    __syncthreads();
    #pragma unroll
    for (int j = 0; j < EPT; j++) {
        int idx = tid + j * 256;
        if (idx < ec) {
            int s = src[e0 + idx];
            int d = dst[e0 + idx];
            bk[j] = d >> CSHIFT;
            pk[j] = s | ((d & (CNODES - 1)) << 17);
            atomicAdd(&hist[bk[j]], 1);
        } else bk[j] = -1;
    }
    __syncthreads();
    const int h = hist[tid];
    exoff[tid] = h;
    __syncthreads();
    for (int dd = 1; dd < 256; dd <<= 1) {
        int v = 0;
        if (tid >= dd) v = exoff[tid - dd];
        __syncthreads();
        if (tid >= dd) exoff[tid] += v;
        __syncthreads();
    }
    const int ex = exoff[tid] - h;
    int gb = 0;
    if (tid < NBUCK && h > 0) gb = atomicAdd(ccur + tid, h);
    __syncthreads();
    exoff[tid] = ex;
    lcur[tid]  = ex;
    gbase[tid] = gb;
    __syncthreads();
    #pragma unroll
    for (int j = 0; j < EPT; j++) {
        if (bk[j] >= 0) {
            int l = atomicAdd(&lcur[bk[j]], 1);
            stage[l]  = pk[j];
            stageB[l] = (unsigned char)bk[j];
        }
    }
    __syncthreads();
    for (int i = tid; i < ec; i += 256) {
        int b = stageB[i];
        pe[gbase[b] + (i - exoff[b])] = stage[i];
    }
}

// One block per coarse bucket: LDS counting sort over 512 nodes -> off/ssrc.
__global__ __launch_bounds__(256) void csr_fine(const int* __restrict__ pe,
                                                const int* __restrict__ coff,
                                                int* __restrict__ off,
                                                int* __restrict__ ssrc, int N) {
    __shared__ int cnt[CNODES];
    __shared__ int cur[CNODES];
    __shared__ int part[256];
    const int b = blockIdx.x;
    const int node0 = b << CSHIFT;
    const int cbeg = coff[b], cend = coff[b + 1];
    const int tid = threadIdx.x;

    cnt[tid] = 0;
    cnt[tid + 256] = 0;
    __syncthreads();
    for (int i = cbeg + tid; i < cend; i += 256)
        atomicAdd(&cnt[(pe[i] >> 17) & (CNODES - 1)], 1);
    __syncthreads();
    const int c0 = cnt[2 * tid], c1 = cnt[2 * tid + 1];
    part[tid] = c0 + c1;
    __syncthreads();
    for (int d = 1; d < 256; d <<= 1) {
        int v = 0;
        if (tid >= d) v = part[tid - d];
        __syncthreads();
        if (tid >= d) part[tid] += v;
        __syncthreads();
    }
    const int ex = (tid > 0) ? part[tid - 1] : 0;
    cur[2 * tid]     = ex;
    cur[2 * tid + 1] = ex + c0;
    if (node0 + 2 * tid     < N) off[node0 + 2 * tid]     = cbeg + ex;
    if (node0 + 2 * tid + 1 < N) off[node0 + 2 * tid + 1] = cbeg + ex + c0;
    __syncthreads();
    for (int i = cbeg + tid; i < cend; i += 256) {
        int p = pe[i];
        int pos = cbeg + atomicAdd(&cur[(p >> 17) & (CNODES - 1)], 1);
        ssrc[pos] = p & 0x1FFFF;
    }
}

// ---------------- aggregation (bf16 gather) ----------------
// 8 lanes per node; each lane owns 8 bf16 elems = 16B load (one dwordx4).
__global__ __launch_bounds__(256) void agg_k(const unsigned short* __restrict__ h,
                                             const int* __restrict__ off,
                                             const int* __restrict__ ssrc,
                                             float* __restrict__ out, int N) {
    int t = blockIdx.x * 256 + threadIdx.x;
    int g = t >> 3;
    if (g >= N) return;
    int q = (t & 7) * 8;
    int beg = off[g], end = off[g + 1];
    float acc[8] = {0.f, 0.f, 0.f, 0.f, 0.f, 0.f, 0.f, 0.f};
    for (int i = beg; i < end; i++) {
        int s = ssrc[i];
        uint4 v = *(const uint4*)(h + (size_t)s * 64 + q);
        acc[0] += __uint_as_float(v.x << 16);
        acc[1] += __uint_as_float(v.x & 0xFFFF0000u);
        acc[2] += __uint_as_float(v.y << 16);
        acc[3] += __uint_as_float(v.y & 0xFFFF0000u);
        acc[4] += __uint_as_float(v.z << 16);
        acc[5] += __uint_as_float(v.z & 0xFFFF0000u);
        acc[6] += __uint_as_float(v.w << 16);
        acc[7] += __uint_as_float(v.w & 0xFFFF0000u);
    }
    float inv = 1.0f / (float)max(end - beg, 1);
    float o[8];
    #pragma unroll
    for (int j = 0; j < 8; j++) o[j] = sigmoidf(acc[j] * inv);
    float* op = out + (size_t)g * 64 + q;
    *(float4*)(op)     = make_float4(o[0], o[1], o[2], o[3]);
    *(float4*)(op + 4) = make_float4(o[4], o[5], o[6], o[7]);
}

// ---------------- GEMM 64x64, fp32 in, bf16 out ----------------
__global__ __launch_bounds__(256) void gemm_bf(
    const float* __restrict__ in, const float* __restrict__ W,
    const float* __restrict__ bias, unsigned short* __restrict__ out, int N)
{
    constexpr int ROWS = 64, TSTR = ROWS + 1;
    __shared__ alignas(16) float Ws[64 * 64];
    __shared__ alignas(16) float Ts[64 * TSTR];
    __shared__ float bs[64];

    const int tid = threadIdx.x;
    {
        const float4* Wg = (const float4*)W;
        float4* Wl = (float4*)Ws;
        #pragma unroll
        for (int i = 0; i < 4; i++) Wl[tid + 256 * i] = Wg[tid + 256 * i];
    }
    if (tid < 64) bs[tid] = bias[tid];

    const int row0 = blockIdx.x * ROWS;
    for (int i = tid; i < 64 * 16; i += 256) {
        int r = i >> 4, c4 = (i & 15) * 4;
        int row = row0 + r;
        float4 v = make_float4(0.f, 0.f, 0.f, 0.f);
        if (row < N) v = *(const float4*)(in + (size_t)row * 64 + c4);
        Ts[(c4 + 0) * TSTR + r] = v.x;
        Ts[(c4 + 1) * TSTR + r] = v.y;
        Ts[(c4 + 2) * TSTR + r] = v.z;
        Ts[(c4 + 3) * TSTR + r] = v.w;
    }
    __syncthreads();

    const int tx = tid & 15, ty = tid >> 4;     // 16x16 threads, 4x4 each
    const int colb = tx * 4, rowb = ty * 4;
    float acc[4][4];
    #pragma unroll
    for (int i = 0; i < 4; i++)
        #pragma unroll
        for (int j = 0; j < 4; j++) acc[i][j] = bs[colb + j];

    for (int k = 0; k < 64; k++) {
        float tv[4];
        #pragma unroll
        for (int i = 0; i < 4; i++) tv[i] = Ts[k * TSTR + rowb + i];
        #pragma unroll
        for (int j = 0; j < 4; j++) {
            float wv = Ws[k * 64 + colb + j];
            #pragma unroll
            for (int i = 0; i < 4; i++) acc[i][j] = fmaf(tv[i], wv, acc[i][j]);
        }
    }

    #pragma unroll
    for (int i = 0; i < 4; i++) {
        int row = row0 + rowb + i;
        if (row < N) {
            ushort4 p;
            p.x = f2bf(acc[i][0]);
            p.y = f2bf(acc[i][1]);
            p.z = f2bf(acc[i][2]);
            p.w = f2bf(acc[i][3]);
            *(ushort4*)(out + (size_t)row * 64 + colb) = p;
        }
    }
}

// ---------------- fused MLP: out = relu(t2@W3+b3)@W4 + b4 ----------------
// 32 rows/block; h3 tile lives only in LDS. ~78KB LDS -> 2 blocks/CU.
__global__ __launch_bounds__(256) void gemm34_k(
    const float* __restrict__ A,   // [N,64] t2
    const float* __restrict__ W3,  // [64,128]
    const float* __restrict__ b3,  // [128]
    const float* __restrict__ W4,  // [128,40]
    const float* __restrict__ b4,  // [40]
    float* __restrict__ out, int N)
{
    __shared__ alignas(16) float Ts[64 * 36];    // A-tile^T [k][r]
    __shared__ alignas(16) float W3s[64 * 128];
    __shared__ alignas(16) float Hs[32 * 132];   // h3 tile [r][k]
    __shared__ alignas(16) float W4s[128 * 40];
    __shared__ float b3s[128];
    __shared__ float b4s[40];

    const int tid = threadIdx.x;
    const int row0 = blockIdx.x * 32;

    {
        const float4* w = (const float4*)W3;
        float4* d = (float4*)W3s;
        #pragma unroll
        for (int i = 0; i < 8; i++) d[tid + 256 * i] = w[tid + 256 * i];
    }
    {
        const float4* w = (const float4*)W4;
        float4* d = (float4*)W4s;
        #pragma unroll
        for (int i = 0; i < 5; i++) d[tid + 256 * i] = w[tid + 256 * i];
    }
    if (tid < 128) b3s[tid] = b3[tid];
    if (tid < 40)  b4s[tid] = b4[tid];
    for (int i = tid; i < 32 * 16; i += 256) {
        int r = i >> 4, c4 = (i & 15) * 4;
        int row = row0 + r;
        float4 v = make_float4(0.f, 0.f, 0.f, 0.f);
        if (row < N) v = *(const float4*)(A + (size_t)row * 64 + c4);
        Ts[(c4 + 0) * 36 + r] = v.x;
        Ts[(c4 + 1) * 36 + r] = v.y;
        Ts[(c4 + 2) * 36 + r] = v.z;
        Ts[(c4 + 3) * 36 + r] = v.w;
    }
    __syncthreads();

    // phase 1: Hs = relu(Ts^T @ W3 + b3)   (32x128)
    {
        const int tx = tid & 31, ty = tid >> 5;  // 32 col-groups x 8 row-groups
        const int colb = tx * 4, rowb = ty * 4;
        float acc[4][4];
        #pragma unroll
        for (int i = 0; i < 4; i++)
            #pragma unroll
            for (int j = 0; j < 4; j++) acc[i][j] = b3s[colb + j];
        for (int k = 0; k < 64; k++) {
            float4 tv = *(const float4*)&Ts[k * 36 + rowb];
            float4 wv = *(const float4*)&W3s[k * 128 + colb];
            const float tvs[4] = {tv.x, tv.y, tv.z, tv.w};
            const float wvs[4] = {wv.x, wv.y, wv.z, wv.w};
            #pragma unroll
            for (int i = 0; i < 4; i++)
                #pragma unroll
                for (int j = 0; j < 4; j++)
                    acc[i][j] = fmaf(tvs[i], wvs[j], acc[i][j]);
        }
        #pragma unroll
        for (int i = 0; i < 4; i++) {
            float4 hv;
            hv.x = fmaxf(acc[i][0], 0.f);
            hv.y = fmaxf(acc[i][1], 0.f);
            hv.z = fmaxf(acc[i][2], 0.f);
            hv.w = fmaxf(acc[i][3], 0.f);
            *(float4*)&Hs[(rowb + i) * 132 + colb] = hv;
        }
    }
    __syncthreads();

    // phase 2: out = Hs @ W4 + b4   (32x40)
    {
        const int tx = tid & 7, ty = tid >> 3;   // ty = row, tx = 5-col group
        const int r = ty, c0 = tx * 5;
        float acc[5];
        #pragma unroll
        for (int j = 0; j < 5; j++) acc[j] = b4s[c0 + j];
        for (int k = 0; k < 128; k++) {
            float hv = Hs[r * 132 + k];
            #pragma unroll
            for (int j = 0; j < 5; j++)
                acc[j] = fmaf(hv, W4s[k * 40 + c0 + j], acc[j]);
        }
        int row = row0 + r;
        if (row < N) {
            #pragma unroll
            for (int j = 0; j < 5; j++) out[(size_t)row * 40 + c0 + j] = acc[j];
        }
    }
}

extern "C" void kernel_launch(void* const* d_in, const int* in_sizes, int n_in,
                              void* d_out, int out_size, void* d_ws, size_t ws_size,
                              hipStream_t stream)
{
    const float* feat = (const float*)d_in[0];
    const int*   eidx = (const int*)d_in[1];
    const float* W1 = (const float*)d_in[2];
    const float* b1 = (const float*)d_in[3];
    const float* W2 = (const float*)d_in[4];
    const float* b2 = (const float*)d_in[5];
    const float* W3 = (const float*)d_in[6];
    const float* b3 = (const float*)d_in[7];
    const float* W4 = (const float*)d_in[8];
    const float* b4 = (const float*)d_in[9];

    const int N = in_sizes[0] / 64;
    const int E = in_sizes[1] / 2;
    const int* src = eidx;
    const int* dst = eidx + E;

    const int NBUCK = (N + CNODES - 1) / CNODES;   // 196

    float*          A   = (float*)d_ws;                      // N*64 f32
    unsigned short* Bh  = (unsigned short*)(A + (size_t)N * 64); // N*64 bf16
    int*   off   = (int*)(Bh + (size_t)N * 64);               // N+1
    int*   chist = off + (N + 1);                             // NBUCK
    int*   coff  = chist + NBUCK;                             // NBUCK+1
    int*   ccur  = coff + (NBUCK + 1);                        // NBUCK
    int*   ssrc  = ccur + NBUCK;                              // E
    int*   pe    = ssrc + E;                                  // E (packed)
    float* out   = (float*)d_out;

    hipMemsetAsync(chist, 0, (size_t)NBUCK * sizeof(int), stream);

    const dim3 blk(256);
    const int gP  = (E + EPB - 1) / EPB;
    const int g64 = (N + 63) / 64;
    const int g34 = (N + 31) / 32;
    const int gAg = (int)(((size_t)N * 8 + 255) / 256);

    // CSR build (shared by both aggregation rounds)
    hist_c<<<gP, blk, 0, stream>>>(dst, chist, E, NBUCK);
    scanc_k<<<1, blk, 0, stream>>>(chist, coff, ccur, off + N, NBUCK, E);
    part_k<<<gP, blk, 0, stream>>>(src, dst, ccur, pe, E, NBUCK);
    csr_fine<<<NBUCK, blk, 0, stream>>>(pe, coff, off, ssrc, N);

    // h1 = feat@W1+b1  (bf16 out)
    gemm_bf<<<g64, blk, 0, stream>>>(feat, W1, b1, Bh, N);
    // t1 = sigmoid(mean h1[src])  (fp32 out)
    agg_k<<<gAg, blk, 0, stream>>>(Bh, off, ssrc, A, N);
    // h2 = t1@W2+b2  (bf16 out)
    gemm_bf<<<g64, blk, 0, stream>>>(A, W2, b2, Bh, N);
    // t2 = sigmoid(mean h2[src])
    agg_k<<<gAg, blk, 0, stream>>>(Bh, off, ssrc, A, N);
    // out = relu(t2@W3+b3)@W4+b4  (fused, h3 never leaves LDS)
    gemm34_k<<<g34, blk, 0, stream>>>(A, W3, b3, W4, b4, out, N);
}

// Round 7
// 302.393 us; speedup vs baseline: 3.6962x; 1.1072x over previous
//
#include <hip/hip_runtime.h>

// HGCN on MI355X. logmap0(expmap0(v)) == v for all vectors occurring here,
// so the model reduces to:
//   h1 = feat@W1+b1; t1 = sigmoid(segmean(h1))
//   h2 = t1@W2+b2;   t2 = sigmoid(segmean(h2))
//   out = relu(t2@W3+b3)@W4 + b4
// R1: fp32 atomicAdd scatter = atomic wall -> counting-sort CSR + gather.
// R2: single-block scan = latency wall -> hierarchical scan.
// R3: 4B random scatter write-allocates 64B lines -> coarse buckets.
// R4: global atomics on few counters = contention wall -> LDS-staged radix.
// R5: agg gather byte-bound -> bf16 rows, fuse MLP, pack CSR.
// R6: fused fp32 MLP is LDS-bound (1.4M bank conflicts, 74us) -> R7: bf16
//     MFMA epilogue; h3 tile lives in LDS; W^T staged with padded strides.

constexpr int CSHIFT = 9;               // 512 nodes per coarse bucket
constexpr int CNODES = 1 << CSHIFT;
constexpr int EPB    = 4096;            // edges per partition block
constexpr int EPT    = EPB / 256;

typedef __attribute__((ext_vector_type(8))) short short8;   // 8 bf16
typedef __attribute__((ext_vector_type(4))) float floatx4;  // MFMA acc

__device__ __forceinline__ float sigmoidf(float x) {
    return 1.0f / (1.0f + __expf(-x));
}
__device__ __forceinline__ unsigned short f2bf(float f) {   // RNE f32->bf16
    unsigned int u = __float_as_uint(f);
    u = (u + 0x7FFFu + ((u >> 16) & 1u)) >> 16;
    return (unsigned short)u;
}

// ---------------- CSR build ----------------

__global__ __launch_bounds__(256) void hist_c(const int* __restrict__ dst,
                                              int* __restrict__ chist,
                                              int E, int NBUCK) {
    __shared__ int h[256];
    const int tid = threadIdx.x;
    h[tid] = 0;
    __syncthreads();
    const int e0 = blockIdx.x * EPB;
    const int ec = min(EPB, E - e0);
    for (int j = 0; j < EPT; j++) {
        int idx = tid + j * 256;
        if (idx < ec) atomicAdd(&h[dst[e0 + idx] >> CSHIFT], 1);
    }
    __syncthreads();
    if (tid < NBUCK && h[tid] > 0) atomicAdd(chist + tid, h[tid]);
}

__global__ __launch_bounds__(256) void scanc_k(const int* __restrict__ chist,
                                               int* __restrict__ coff,
                                               int* __restrict__ ccur,
                                               int* __restrict__ offN,
                                               int NBUCK, int E) {
    __shared__ int sh[256];
    const int tid = threadIdx.x;
    sh[tid] = (tid < NBUCK) ? chist[tid] : 0;
    __syncthreads();
    for (int d = 1; d < 256; d <<= 1) {
        int v = 0;
        if (tid >= d) v = sh[tid - d];
        __syncthreads();
        if (tid >= d) sh[tid] += v;
        __syncthreads();
    }
    if (tid < NBUCK) {
        int ex = (tid > 0) ? sh[tid - 1] : 0;
        coff[tid] = ex;
        ccur[tid] = ex;
    }
    if (tid == 0) { coff[NBUCK] = E; *offN = E; }
}

__global__ __launch_bounds__(256) void part_k(const int* __restrict__ src,
                                              const int* __restrict__ dst,
                                              int* __restrict__ ccur,
                                              int* __restrict__ pe,
                                              int E, int NBUCK) {
    __shared__ int  hist[256];
    __shared__ int  exoff[256];
    __shared__ int  lcur[256];
    __shared__ int  gbase[256];
    __shared__ int  stage[EPB];
    __shared__ unsigned char stageB[EPB];

    const int tid = threadIdx.x;
    const int e0  = blockIdx.x * EPB;
    const int ec  = min(EPB, E - e0);

    int pk[EPT], bk[EPT];
    hist[tid] = 0;
    __syncthreads();
    #pragma unroll
    for (int j = 0; j < EPT; j++) {
        int idx = tid + j * 256;
        if (idx < ec) {
            int s = src[e0 + idx];
            int d = dst[e0 + idx];
            bk[j] = d >> CSHIFT;
            pk[j] = s | ((d & (CNODES - 1)) << 17);
            atomicAdd(&hist[bk[j]], 1);
        } else bk[j] = -1;
    }
    __syncthreads();
    const int h = hist[tid];
    exoff[tid] = h;
    __syncthreads();
    for (int dd = 1; dd < 256; dd <<= 1) {
        int v = 0;
        if (tid >= dd) v = exoff[tid - dd];
        __syncthreads();
        if (tid >= dd) exoff[tid] += v;
        __syncthreads();
    }
    const int ex = exoff[tid] - h;
    int gb = 0;
    if (tid < NBUCK && h > 0) gb = atomicAdd(ccur + tid, h);
    __syncthreads();
    exoff[tid] = ex;
    lcur[tid]  = ex;
    gbase[tid] = gb;
    __syncthreads();
    #pragma unroll
    for (int j = 0; j < EPT; j++) {
        if (bk[j] >= 0) {
            int l = atomicAdd(&lcur[bk[j]], 1);
            stage[l]  = pk[j];
            stageB[l] = (unsigned char)bk[j];
        }
    }
    __syncthreads();
    for (int i = tid; i < ec; i += 256) {
        int b = stageB[i];
        pe[gbase[b] + (i - exoff[b])] = stage[i];
    }
}

__global__ __launch_bounds__(256) void csr_fine(const int* __restrict__ pe,
                                                const int* __restrict__ coff,
                                                int* __restrict__ off,
                                                int* __restrict__ ssrc, int N) {
    __shared__ int cnt[CNODES];
    __shared__ int cur[CNODES];
    __shared__ int part[256];
    const int b = blockIdx.x;
    const int node0 = b << CSHIFT;
    const int cbeg = coff[b], cend = coff[b + 1];
    const int tid = threadIdx.x;

    cnt[tid] = 0;
    cnt[tid + 256] = 0;
    __syncthreads();
    for (int i = cbeg + tid; i < cend; i += 256)
        atomicAdd(&cnt[(pe[i] >> 17) & (CNODES - 1)], 1);
    __syncthreads();
    const int c0 = cnt[2 * tid], c1 = cnt[2 * tid + 1];
    part[tid] = c0 + c1;
    __syncthreads();
    for (int d = 1; d < 256; d <<= 1) {
        int v = 0;
        if (tid >= d) v = part[tid - d];
        __syncthreads();
        if (tid >= d) part[tid] += v;
        __syncthreads();
    }
    const int ex = (tid > 0) ? part[tid - 1] : 0;
    cur[2 * tid]     = ex;
    cur[2 * tid + 1] = ex + c0;
    if (node0 + 2 * tid     < N) off[node0 + 2 * tid]     = cbeg + ex;
    if (node0 + 2 * tid + 1 < N) off[node0 + 2 * tid + 1] = cbeg + ex + c0;
    __syncthreads();
    for (int i = cbeg + tid; i < cend; i += 256) {
        int p = pe[i];
        int pos = cbeg + atomicAdd(&cur[(p >> 17) & (CNODES - 1)], 1);
        ssrc[pos] = p & 0x1FFFF;
    }
}

// ---------------- aggregation (bf16 gather) ----------------
// 8 lanes per node; lane owns 8 bf16 = one 16B load. BF16OUT: emit bf16.
template<bool BF16OUT>
__global__ __launch_bounds__(256) void agg_k(const unsigned short* __restrict__ h,
                                             const int* __restrict__ off,
                                             const int* __restrict__ ssrc,
                                             float* __restrict__ outf,
                                             unsigned short* __restrict__ outb,
                                             int N) {
    int t = blockIdx.x * 256 + threadIdx.x;
    int g = t >> 3;
    if (g >= N) return;
    int q = (t & 7) * 8;
    int beg = off[g], end = off[g + 1];
    float acc[8] = {0.f, 0.f, 0.f, 0.f, 0.f, 0.f, 0.f, 0.f};
    for (int i = beg; i < end; i++) {
        int s = ssrc[i];
        uint4 v = *(const uint4*)(h + (size_t)s * 64 + q);
        acc[0] += __uint_as_float(v.x << 16);
        acc[1] += __uint_as_float(v.x & 0xFFFF0000u);
        acc[2] += __uint_as_float(v.y << 16);
        acc[3] += __uint_as_float(v.y & 0xFFFF0000u);
        acc[4] += __uint_as_float(v.z << 16);
        acc[5] += __uint_as_float(v.z & 0xFFFF0000u);
        acc[6] += __uint_as_float(v.w << 16);
        acc[7] += __uint_as_float(v.w & 0xFFFF0000u);
    }
    float inv = 1.0f / (float)max(end - beg, 1);
    float o[8];
    #pragma unroll
    for (int j = 0; j < 8; j++) o[j] = sigmoidf(acc[j] * inv);
    if (BF16OUT) {
        uint4 p;
        p.x = (unsigned)f2bf(o[0]) | ((unsigned)f2bf(o[1]) << 16);
        p.y = (unsigned)f2bf(o[2]) | ((unsigned)f2bf(o[3]) << 16);
        p.z = (unsigned)f2bf(o[4]) | ((unsigned)f2bf(o[5]) << 16);
        p.w = (unsigned)f2bf(o[6]) | ((unsigned)f2bf(o[7]) << 16);
        *(uint4*)(outb + (size_t)g * 64 + q) = p;
    } else {
        float* op = outf + (size_t)g * 64 + q;
        *(float4*)(op)     = make_float4(o[0], o[1], o[2], o[3]);
        *(float4*)(op + 4) = make_float4(o[4], o[5], o[6], o[7]);
    }
}

// ---------------- GEMM 64x64, fp32 in, bf16 out (vector FMA) ----------------
__global__ __launch_bounds__(256) void gemm_bf(
    const float* __restrict__ in, const float* __restrict__ W,
    const float* __restrict__ bias, unsigned short* __restrict__ out, int N)
{
    constexpr int ROWS = 64, TSTR = ROWS + 1;
    __shared__ alignas(16) float Ws[64 * 64];
    __shared__ alignas(16) float Ts[64 * TSTR];
    __shared__ float bs[64];

    const int tid = threadIdx.x;
    {
        const float4* Wg = (const float4*)W;
        float4* Wl = (float4*)Ws;
        #pragma unroll
        for (int i = 0; i < 4; i++) Wl[tid + 256 * i] = Wg[tid + 256 * i];
    }
    if (tid < 64) bs[tid] = bias[tid];

    const int row0 = blockIdx.x * ROWS;
    for (int i = tid; i < 64 * 16; i += 256) {
        int r = i >> 4, c4 = (i & 15) * 4;
        int row = row0 + r;
        float4 v = make_float4(0.f, 0.f, 0.f, 0.f);
        if (row < N) v = *(const float4*)(in + (size_t)row * 64 + c4);
        Ts[(c4 + 0) * TSTR + r] = v.x;
        Ts[(c4 + 1) * TSTR + r] = v.y;
        Ts[(c4 + 2) * TSTR + r] = v.z;
        Ts[(c4 + 3) * TSTR + r] = v.w;
    }
    __syncthreads();

    const int tx = tid & 15, ty = tid >> 4;
    const int colb = tx * 4, rowb = ty * 4;
    float acc[4][4];
    #pragma unroll
    for (int i = 0; i < 4; i++)
        #pragma unroll
        for (int j = 0; j < 4; j++) acc[i][j] = bs[colb + j];

    for (int k = 0; k < 64; k++) {
        float tv[4];
        #pragma unroll
        for (int i = 0; i < 4; i++) tv[i] = Ts[k * TSTR + rowb + i];
        #pragma unroll
        for (int j = 0; j < 4; j++) {
            float wv = Ws[k * 64 + colb + j];
            #pragma unroll
            for (int i = 0; i < 4; i++) acc[i][j] = fmaf(tv[i], wv, acc[i][j]);
        }
    }

    #pragma unroll
    for (int i = 0; i < 4; i++) {
        int row = row0 + rowb + i;
        if (row < N) {
            ushort4 p;
            p.x = f2bf(acc[i][0]);
            p.y = f2bf(acc[i][1]);
            p.z = f2bf(acc[i][2]);
            p.w = f2bf(acc[i][3]);
            *(ushort4*)(out + (size_t)row * 64 + colb) = p;
        }
    }
}

// ---------------- MFMA epilogue: out = relu(t2@W3+b3)@W4 + b4 ----------------
// 64 rows/block, 4 waves x 16 rows. h3 tile lives only in LDS (bf16).
// LDS strides padded for 2-way-max bank aliasing (free per m136) and 16B align.
__global__ __launch_bounds__(256) void mfma_ep(
    const unsigned short* __restrict__ Abf,  // [N,64] t2 bf16
    const float* __restrict__ W3, const float* __restrict__ b3,
    const float* __restrict__ W4, const float* __restrict__ b4,
    float* __restrict__ out, int N)
{
    constexpr int W3S = 72;    // shorts; 144B rows (16B-aligned, stride%32dw=4)
    constexpr int HS  = 136;   // shorts; 272B rows
    constexpr int W4S = 136;
    __shared__ alignas(16) unsigned short W3T[128 * W3S];  // 18.4 KB
    __shared__ alignas(16) unsigned short W4T[48 * W4S];   // 13.1 KB
    __shared__ alignas(16) unsigned short H3[64 * HS];     // 17.4 KB
    __shared__ float b3s[128];
    __shared__ float b4s[48];

    const int tid = threadIdx.x;
    // stage W3T[n][k] = bf16(W3[k][n])  (W3 is [64][128] row-major)
    for (int i = tid; i < 64 * 128; i += 256) {
        int k = i >> 7, n = i & 127;
        W3T[n * W3S + k] = f2bf(W3[i]);
    }
    // stage W4T[n][k] = bf16(W4[k][n]), zero-pad n in [40,48)
    for (int i = tid; i < 48 * 128; i += 256) {
        int n = i >> 7, k = i & 127;
        W4T[n * W4S + k] = (n < 40) ? f2bf(W4[k * 40 + n]) : (unsigned short)0;
    }
    if (tid < 128) b3s[tid] = b3[tid];
    if (tid < 48)  b4s[tid] = (tid < 40) ? b4[tid] : 0.f;
    __syncthreads();

    const int w = tid >> 6, lane = tid & 63;
    const int m = lane & 15, quad = lane >> 4;
    const int row0 = blockIdx.x * 64 + w * 16;

    // ---- phase 1: H3(16 rows/wave x 128) = relu(A @ W3 + b3) ----
    floatx4 acc[8];
    #pragma unroll
    for (int c = 0; c < 8; c++) acc[c] = (floatx4){0.f, 0.f, 0.f, 0.f};
    const int arow = min(row0 + m, N - 1);      // clamp tail (stores masked)
    #pragma unroll
    for (int kk = 0; kk < 64; kk += 32) {
        short8 a = *(const short8*)(Abf + (size_t)arow * 64 + kk + quad * 8);
        #pragma unroll
        for (int c = 0; c < 8; c++) {
            short8 b = *(const short8*)(W3T + (c * 16 + m) * W3S + kk + quad * 8);
            acc[c] = __builtin_amdgcn_mfma_f32_16x16x32_bf16(a, b, acc[c], 0, 0, 0);
        }
    }
    #pragma unroll
    for (int c = 0; c < 8; c++) {
        #pragma unroll
        for (int r = 0; r < 4; r++) {
            int orow = w * 16 + quad * 4 + r;
            int col  = c * 16 + m;
            H3[orow * HS + col] = f2bf(fmaxf(acc[c][r] + b3s[col], 0.f));
        }
    }
    __syncthreads();

    // ---- phase 2: out(16 rows/wave x 40) = H3 @ W4 + b4 ----
    floatx4 acc2[3];
    #pragma unroll
    for (int c = 0; c < 3; c++) acc2[c] = (floatx4){0.f, 0.f, 0.f, 0.f};
    #pragma unroll
    for (int kk = 0; kk < 128; kk += 32) {
        short8 a = *(const short8*)(H3 + (w * 16 + m) * HS + kk + quad * 8);
        #pragma unroll
        for (int c = 0; c < 3; c++) {
            short8 b = *(const short8*)(W4T + (c * 16 + m) * W4S + kk + quad * 8);
            acc2[c] = __builtin_amdgcn_mfma_f32_16x16x32_bf16(a, b, acc2[c], 0, 0, 0);
        }
    }
    #pragma unroll
    for (int c = 0; c < 3; c++) {
        int col = c * 16 + m;
        if (col < 40) {
            #pragma unroll
            for (int r = 0; r < 4; r++) {
                int row = row0 + quad * 4 + r;
                if (row < N) out[(size_t)row * 40 + col] = acc2[c][r] + b4s[col];
            }
        }
    }
}

extern "C" void kernel_launch(void* const* d_in, const int* in_sizes, int n_in,
                              void* d_out, int out_size, void* d_ws, size_t ws_size,
                              hipStream_t stream)
{
    const float* feat = (const float*)d_in[0];
    const int*   eidx = (const int*)d_in[1];
    const float* W1 = (const float*)d_in[2];
    const float* b1 = (const float*)d_in[3];
    const float* W2 = (const float*)d_in[4];
    const float* b2 = (const float*)d_in[5];
    const float* W3 = (const float*)d_in[6];
    const float* b3 = (const float*)d_in[7];
    const float* W4 = (const float*)d_in[8];
    const float* b4 = (const float*)d_in[9];

    const int N = in_sizes[0] / 64;
    const int E = in_sizes[1] / 2;
    const int* src = eidx;
    const int* dst = eidx + E;

    const int NBUCK = (N + CNODES - 1) / CNODES;   // 196

    float*          A   = (float*)d_ws;                          // N*64 f32 (t1)
    unsigned short* Bh  = (unsigned short*)(A + (size_t)N * 64); // N*64 bf16 (h)
    unsigned short* Abf = Bh + (size_t)N * 64;                   // N*64 bf16 (t2)
    int*   off   = (int*)(Abf + (size_t)N * 64);                 // N+1
    int*   chist = off + (N + 1);                                // NBUCK
    int*   coff  = chist + NBUCK;                                // NBUCK+1
    int*   ccur  = coff + (NBUCK + 1);                           // NBUCK
    int*   ssrc  = ccur + NBUCK;                                 // E
    int*   pe    = ssrc + E;                                     // E (packed)
    float* out   = (float*)d_out;

    hipMemsetAsync(chist, 0, (size_t)NBUCK * sizeof(int), stream);

    const dim3 blk(256);
    const int gP  = (E + EPB - 1) / EPB;
    const int g64 = (N + 63) / 64;
    const int gAg = (int)(((size_t)N * 8 + 255) / 256);

    // CSR build (shared by both aggregation rounds)
    hist_c<<<gP, blk, 0, stream>>>(dst, chist, E, NBUCK);
    scanc_k<<<1, blk, 0, stream>>>(chist, coff, ccur, off + N, NBUCK, E);
    part_k<<<gP, blk, 0, stream>>>(src, dst, ccur, pe, E, NBUCK);
    csr_fine<<<NBUCK, blk, 0, stream>>>(pe, coff, off, ssrc, N);

    // h1 = feat@W1+b1  (bf16 out)
    gemm_bf<<<g64, blk, 0, stream>>>(feat, W1, b1, Bh, N);
    // t1 = sigmoid(mean h1[src])  (fp32 out -> gemm_bf)
    agg_k<false><<<gAg, blk, 0, stream>>>(Bh, off, ssrc, A, nullptr, N);
    // h2 = t1@W2+b2  (bf16 out)
    gemm_bf<<<g64, blk, 0, stream>>>(A, W2, b2, Bh, N);
    // t2 = sigmoid(mean h2[src])  (bf16 out -> MFMA epilogue)
    agg_k<true><<<gAg, blk, 0, stream>>>(Bh, off, ssrc, nullptr, Abf, N);
    // out = relu(t2@W3+b3)@W4+b4  (MFMA, h3 never leaves LDS)
    mfma_ep<<<g64, blk, 0, stream>>>(Abf, W3, b3, W4, b4, out, N);
}

// Round 8
// 261.433 us; speedup vs baseline: 4.2753x; 1.1567x over previous
//
#include <hip/hip_runtime.h>

// HGCN on MI355X. logmap0(expmap0(v)) == v for all vectors occurring here,
// so the model reduces to:
//   t1 = sigmoid(segmean(feat@W1+b1)); t2 = sigmoid(segmean(t1@W2+b2))
//   out = relu(t2@W3+b3)@W4 + b4
// R1: fp32 atomicAdd scatter = atomic wall -> counting-sort CSR + gather.
// R2: single-block scan = latency wall -> hierarchical scan.
// R3: 4B random scatter write-allocates 64B lines -> coarse buckets.
// R4: global atomics on few counters = contention wall -> LDS-staged radix.
// R5: agg gather byte-bound -> bf16 rows, pack CSR.
// R6: fp32 MLP LDS-bound -> MFMA epilogue.
// R8: aggregation is linear -> aggregate BEFORE GEMM (mean(h[src]) =
//     mean(t[src])@W + b, deg-0 nodes flagged); all GEMMs become bf16 MFMA
//     w/ fused sigmoid; gemm2..4 fuse into one kernel; agg unrolled x4;
//     hist pass deleted via fixed-capacity bucket arena.

constexpr int CSHIFT = 9;               // 512 nodes per coarse bucket
constexpr int CNODES = 1 << CSHIFT;
constexpr int EPB    = 4096;            // edges per partition block
constexpr int EPT    = EPB / 256;
constexpr int CAP    = 16384;           // arena capacity per bucket (mean 8163)

typedef __attribute__((ext_vector_type(8))) short short8;   // 8 bf16
typedef __attribute__((ext_vector_type(4))) float floatx4;  // MFMA acc

__device__ __forceinline__ float sigmoidf(float x) {
    return 1.0f / (1.0f + __expf(-x));
}
__device__ __forceinline__ unsigned short f2bf(float f) {   // RNE f32->bf16
    unsigned int u = __float_as_uint(f);
    u = (u + 0x7FFFu + ((u >> 16) & 1u)) >> 16;
    return (unsigned short)u;
}

// ---------------- cast feat -> bf16 ----------------
__global__ __launch_bounds__(256) void cast_k(const float* __restrict__ in,
                                              unsigned short* __restrict__ out,
                                              int n8) {
    int i = blockIdx.x * 256 + threadIdx.x;
    if (i >= n8) return;
    const float4* p = (const float4*)in + (size_t)i * 2;
    float4 a = p[0], b = p[1];
    uint4 o;
    o.x = (unsigned)f2bf(a.x) | ((unsigned)f2bf(a.y) << 16);
    o.y = (unsigned)f2bf(a.z) | ((unsigned)f2bf(a.w) << 16);
    o.z = (unsigned)f2bf(b.x) | ((unsigned)f2bf(b.y) << 16);
    o.w = (unsigned)f2bf(b.z) | ((unsigned)f2bf(b.w) << 16);
    ((uint4*)out)[i] = o;
}

// ---------------- CSR build ----------------
// Radix partition into per-bucket arena regions (no prior histogram pass):
// per-block LDS hist -> scan -> reserve arena space (<=196 global atomics)
// -> LDS staging reorder -> dense write-out of packed (src | ldst<<17).
__global__ __launch_bounds__(256) void part_a(const int* __restrict__ src,
                                              const int* __restrict__ dst,
                                              int* __restrict__ ccur,
                                              int* __restrict__ arena,
                                              int E, int NBUCK) {
    __shared__ int  hist[256];
    __shared__ int  exoff[256];
    __shared__ int  lcur[256];
    __shared__ int  gbase[256];
    __shared__ int  stage[EPB];
    __shared__ unsigned char stageB[EPB];

    const int tid = threadIdx.x;
    const int e0  = blockIdx.x * EPB;
    const int ec  = min(EPB, E - e0);

    int pk[EPT], bk[EPT];
    hist[tid] = 0;
    __syncthreads();
    #pragma unroll
    for (int j = 0; j < EPT; j++) {
        int idx = tid + j * 256;
        if (idx < ec) {
            int s = src[e0 + idx];
            int d = dst[e0 + idx];
            bk[j] = d >> CSHIFT;
            pk[j] = s | ((d & (CNODES - 1)) << 17);
            atomicAdd(&hist[bk[j]], 1);
        } else bk[j] = -1;
    }
    __syncthreads();
    const int h = hist[tid];
    exoff[tid] = h;
    __syncthreads();
    for (int dd = 1; dd < 256; dd <<= 1) {
        int v = 0;
        if (tid >= dd) v = exoff[tid - dd];
        __syncthreads();
        if (tid >= dd) exoff[tid] += v;
        __syncthreads();
    }
    const int ex = exoff[tid] - h;
    int gb = 0;
    if (tid < NBUCK && h > 0) gb = atomicAdd(ccur + tid, h);
    __syncthreads();
    exoff[tid] = ex;
    lcur[tid]  = ex;
    gbase[tid] = gb;
    __syncthreads();
    #pragma unroll
    for (int j = 0; j < EPT; j++) {
        if (bk[j] >= 0) {
            int l = atomicAdd(&lcur[bk[j]], 1);
            stage[l]  = pk[j];
            stageB[l] = (unsigned char)bk[j];
        }
    }
    __syncthreads();
    for (int i = tid; i < ec; i += 256) {
        int b = stageB[i];
        arena[(size_t)b * CAP + gbase[b] + (i - exoff[b])] = stage[i];
    }
}

// Scan bucket counts (= final cursors) -> compact exclusive offsets coff.
__global__ __launch_bounds__(256) void scanc_k(const int* __restrict__ ccur,
                                               int* __restrict__ coff,
                                               int* __restrict__ offN,
                                               int NBUCK, int E) {
    __shared__ int sh[256];
    const int tid = threadIdx.x;
    sh[tid] = (tid < NBUCK) ? ccur[tid] : 0;
    __syncthreads();
    for (int d = 1; d < 256; d <<= 1) {
        int v = 0;
        if (tid >= d) v = sh[tid - d];
        __syncthreads();
        if (tid >= d) sh[tid] += v;
        __syncthreads();
    }
    if (tid < NBUCK) coff[tid] = (tid > 0) ? sh[tid - 1] : 0;
    if (tid == 0) { coff[NBUCK] = E; *offN = E; }
}

// One block per coarse bucket: LDS counting sort over 512 nodes -> off/ssrc.
__global__ __launch_bounds__(256) void csr_fine(const int* __restrict__ arena,
                                                const int* __restrict__ coff,
                                                int* __restrict__ off,
                                                int* __restrict__ ssrc, int N) {
    __shared__ int cnt[CNODES];
    __shared__ int cur[CNODES];
    __shared__ int part[256];
    const int b = blockIdx.x;
    const int node0 = b << CSHIFT;
    const int cbeg = coff[b];
    const int ec   = coff[b + 1] - cbeg;
    const int* pe  = arena + (size_t)b * CAP;
    const int tid = threadIdx.x;

    cnt[tid] = 0;
    cnt[tid + 256] = 0;
    __syncthreads();
    for (int i = tid; i < ec; i += 256)
        atomicAdd(&cnt[(pe[i] >> 17) & (CNODES - 1)], 1);
    __syncthreads();
    const int c0 = cnt[2 * tid], c1 = cnt[2 * tid + 1];
    part[tid] = c0 + c1;
    __syncthreads();
    for (int d = 1; d < 256; d <<= 1) {
        int v = 0;
        if (tid >= d) v = part[tid - d];
        __syncthreads();
        if (tid >= d) part[tid] += v;
        __syncthreads();
    }
    const int ex = (tid > 0) ? part[tid - 1] : 0;
    cur[2 * tid]     = ex;
    cur[2 * tid + 1] = ex + c0;
    if (node0 + 2 * tid     < N) off[node0 + 2 * tid]     = cbeg + ex;
    if (node0 + 2 * tid + 1 < N) off[node0 + 2 * tid + 1] = cbeg + ex + c0;
    __syncthreads();
    for (int i = tid; i < ec; i += 256) {
        int p = pe[i];
        int pos = cbeg + atomicAdd(&cur[(p >> 17) & (CNODES - 1)], 1);
        ssrc[pos] = p & 0x1FFFF;
    }
}

// ---------------- aggregation: pure mean gather, bf16->bf16 ----------------
// 8 lanes per node; lane owns 8 bf16 = one 16B load. Unroll x4 (4 gathers
// in flight per lane) to attack the latency-bound regime seen in R7.
#define ACC8(v)                                    \
    acc[0] += __uint_as_float((v).x << 16);        \
    acc[1] += __uint_as_float((v).x & 0xFFFF0000u);\
    acc[2] += __uint_as_float((v).y << 16);        \
    acc[3] += __uint_as_float((v).y & 0xFFFF0000u);\
    acc[4] += __uint_as_float((v).z << 16);        \
    acc[5] += __uint_as_float((v).z & 0xFFFF0000u);\
    acc[6] += __uint_as_float((v).w << 16);        \
    acc[7] += __uint_as_float((v).w & 0xFFFF0000u);

__global__ __launch_bounds__(256) void agg_k(const unsigned short* __restrict__ h,
                                             const int* __restrict__ off,
                                             const int* __restrict__ ssrc,
                                             unsigned short* __restrict__ outb,
                                             int N) {
    int t = blockIdx.x * 256 + threadIdx.x;
    int g = t >> 3;
    if (g >= N) return;
    int q = (t & 7) * 8;
    int beg = off[g], end = off[g + 1];
    float acc[8] = {0.f, 0.f, 0.f, 0.f, 0.f, 0.f, 0.f, 0.f};
    int i = beg;
    for (; i + 4 <= end; i += 4) {
        int s0 = ssrc[i], s1 = ssrc[i + 1], s2 = ssrc[i + 2], s3 = ssrc[i + 3];
        uint4 v0 = *(const uint4*)(h + (size_t)s0 * 64 + q);
        uint4 v1 = *(const uint4*)(h + (size_t)s1 * 64 + q);
        uint4 v2 = *(const uint4*)(h + (size_t)s2 * 64 + q);
        uint4 v3 = *(const uint4*)(h + (size_t)s3 * 64 + q);
        ACC8(v0); ACC8(v1); ACC8(v2); ACC8(v3);
    }
    for (; i < end; i++) {
        int s = ssrc[i];
        uint4 v = *(const uint4*)(h + (size_t)s * 64 + q);
        ACC8(v);
    }
    float inv = 1.0f / (float)max(end - beg, 1);
    uint4 p;
    p.x = (unsigned)f2bf(acc[0] * inv) | ((unsigned)f2bf(acc[1] * inv) << 16);
    p.y = (unsigned)f2bf(acc[2] * inv) | ((unsigned)f2bf(acc[3] * inv) << 16);
    p.z = (unsigned)f2bf(acc[4] * inv) | ((unsigned)f2bf(acc[5] * inv) << 16);
    p.w = (unsigned)f2bf(acc[6] * inv) | ((unsigned)f2bf(acc[7] * inv) << 16);
    *(uint4*)(outb + (size_t)g * 64 + q) = p;
}

// ---------------- MFMA GEMM 64x64 + sigmoid: t = sigmoid(agg@W+b) ----------
// deg-0 nodes: mean(h[src]) over empty set is 0 in the reference, so the
// true value is sigmoid(0)=0.5, NOT sigmoid(b) -> override via dz flag.
__global__ __launch_bounds__(256) void gemmsig_k(
    const unsigned short* __restrict__ Abf, const int* __restrict__ off,
    const float* __restrict__ W, const float* __restrict__ bias,
    unsigned short* __restrict__ out, int N)
{
    constexpr int WS = 72;
    __shared__ alignas(16) unsigned short WT[64 * WS];
    __shared__ float bs[64];
    __shared__ unsigned char dz[64];

    const int tid = threadIdx.x;
    const int rowB = blockIdx.x * 64;
    for (int i = tid; i < 64 * 64; i += 256) {
        int k = i >> 6, n = i & 63;
        WT[n * WS + k] = f2bf(W[i]);
    }
    if (tid < 64) {
        bs[tid] = bias[tid];
        int row = rowB + tid;
        dz[tid] = (row < N) ? (off[row + 1] == off[row]) : 0;
    }
    __syncthreads();

    const int w = tid >> 6, lane = tid & 63;
    const int m = lane & 15, quad = lane >> 4;
    const int row0 = rowB + w * 16;
    const int arow = min(row0 + m, N - 1);

    floatx4 acc[4];
    #pragma unroll
    for (int c = 0; c < 4; c++) acc[c] = (floatx4){0.f, 0.f, 0.f, 0.f};
    #pragma unroll
    for (int kk = 0; kk < 64; kk += 32) {
        short8 a = *(const short8*)(Abf + (size_t)arow * 64 + kk + quad * 8);
        #pragma unroll
        for (int c = 0; c < 4; c++) {
            short8 b = *(const short8*)(WT + (c * 16 + m) * WS + kk + quad * 8);
            acc[c] = __builtin_amdgcn_mfma_f32_16x16x32_bf16(a, b, acc[c], 0, 0, 0);
        }
    }
    #pragma unroll
    for (int c = 0; c < 4; c++) {
        int col = c * 16 + m;
        #pragma unroll
        for (int r = 0; r < 4; r++) {
            int rl = w * 16 + quad * 4 + r;
            int row = rowB + rl;
            if (row < N) {
                float v = dz[rl] ? 0.5f : sigmoidf(acc[c][r] + bs[col]);
                out[(size_t)row * 64 + col] = f2bf(v);
            }
        }
    }
}

// ---------------- fused triple-GEMM epilogue ----------------
// t2 = sigmoid(aggF2@W2+b2); h3 = relu(t2@W3+b3); out = h3@W4+b4.
// t2 and h3 tiles live only in LDS. ~68 KB LDS -> 2 blocks/CU.
__global__ __launch_bounds__(256) void ep3_k(
    const unsigned short* __restrict__ Abf, const int* __restrict__ off,
    const float* __restrict__ W2, const float* __restrict__ b2,
    const float* __restrict__ W3, const float* __restrict__ b3,
    const float* __restrict__ W4, const float* __restrict__ b4,
    float* __restrict__ out, int N)
{
    constexpr int W2S = 72, W3S = 72, HS = 136, W4S = 136, T2S = 72;
    __shared__ alignas(16) unsigned short W2T[64 * W2S];    // 9.2 KB
    __shared__ alignas(16) unsigned short W3T[128 * W3S];   // 18.4 KB
    __shared__ alignas(16) unsigned short W4T[48 * W4S];    // 13.1 KB
    __shared__ alignas(16) unsigned short T2[64 * T2S];     // 9.2 KB
    __shared__ alignas(16) unsigned short H3[64 * HS];      // 17.4 KB
    __shared__ float b2s[64], b3s[128], b4s[48];
    __shared__ unsigned char dz[64];

    const int tid = threadIdx.x;
    const int rowB = blockIdx.x * 64;
    for (int i = tid; i < 64 * 64; i += 256) {
        int k = i >> 6, n = i & 63;
        W2T[n * W2S + k] = f2bf(W2[i]);
    }
    for (int i = tid; i < 64 * 128; i += 256) {
        int k = i >> 7, n = i & 127;
        W3T[n * W3S + k] = f2bf(W3[i]);
    }
    for (int i = tid; i < 48 * 128; i += 256) {
        int n = i >> 7, k = i & 127;
        W4T[n * W4S + k] = (n < 40) ? f2bf(W4[k * 40 + n]) : (unsigned short)0;
    }
    if (tid < 64) {
        b2s[tid] = b2[tid];
        int row = rowB + tid;
        dz[tid] = (row < N) ? (off[row + 1] == off[row]) : 0;
    }
    if (tid < 128) b3s[tid] = b3[tid];
    if (tid < 48)  b4s[tid] = (tid < 40) ? b4[tid] : 0.f;
    __syncthreads();

    const int w = tid >> 6, lane = tid & 63;
    const int m = lane & 15, quad = lane >> 4;
    const int row0 = rowB + w * 16;

    // ---- phase 0: T2 = sigmoid(aggF2 @ W2 + b2) ----
    {
        floatx4 acc[4];
        #pragma unroll
        for (int c = 0; c < 4; c++) acc[c] = (floatx4){0.f, 0.f, 0.f, 0.f};
        const int arow = min(row0 + m, N - 1);
        #pragma unroll
        for (int kk = 0; kk < 64; kk += 32) {
            short8 a = *(const short8*)(Abf + (size_t)arow * 64 + kk + quad * 8);
            #pragma unroll
            for (int c = 0; c < 4; c++) {
                short8 b = *(const short8*)(W2T + (c * 16 + m) * W2S + kk + quad * 8);
                acc[c] = __builtin_amdgcn_mfma_f32_16x16x32_bf16(a, b, acc[c], 0, 0, 0);
            }
        }
        #pragma unroll
        for (int c = 0; c < 4; c++) {
            int col = c * 16 + m;
            #pragma unroll
            for (int r = 0; r < 4; r++) {
                int rl = w * 16 + quad * 4 + r;
                float v = dz[rl] ? 0.5f : sigmoidf(acc[c][r] + b2s[col]);
                T2[rl * T2S + col] = f2bf(v);
            }
        }
    }
    __syncthreads();

    // ---- phase 1: H3 = relu(T2 @ W3 + b3) ----
    {
        floatx4 acc[8];
        #pragma unroll
        for (int c = 0; c < 8; c++) acc[c] = (floatx4){0.f, 0.f, 0.f, 0.f};
        #pragma unroll
        for (int kk = 0; kk < 64; kk += 32) {
            short8 a = *(const short8*)(T2 + (w * 16 + m) * T2S + kk + quad * 8);
            #pragma unroll
            for (int c = 0; c < 8; c++) {
                short8 b = *(const short8*)(W3T + (c * 16 + m) * W3S + kk + quad * 8);
                acc[c] = __builtin_amdgcn_mfma_f32_16x16x32_bf16(a, b, acc[c], 0, 0, 0);
            }
        }
        #pragma unroll
        for (int c = 0; c < 8; c++) {
            int col = c * 16 + m;
            #pragma unroll
            for (int r = 0; r < 4; r++) {
                int rl = w * 16 + quad * 4 + r;
                H3[rl * HS + col] = f2bf(fmaxf(acc[c][r] + b3s[col], 0.f));
            }
        }
    }
    __syncthreads();

    // ---- phase 2: out = H3 @ W4 + b4 ----
    {
        floatx4 acc[3];
        #pragma unroll
        for (int c = 0; c < 3; c++) acc[c] = (floatx4){0.f, 0.f, 0.f, 0.f};
        #pragma unroll
        for (int kk = 0; kk < 128; kk += 32) {
            short8 a = *(const short8*)(H3 + (w * 16 + m) * HS + kk + quad * 8);
            #pragma unroll
            for (int c = 0; c < 3; c++) {
                short8 b = *(const short8*)(W4T + (c * 16 + m) * W4S + kk + quad * 8);
                acc[c] = __builtin_amdgcn_mfma_f32_16x16x32_bf16(a, b, acc[c], 0, 0, 0);
            }
        }
        #pragma unroll
        for (int c = 0; c < 3; c++) {
            int col = c * 16 + m;
            if (col < 40) {
                #pragma unroll
                for (int r = 0; r < 4; r++) {
                    int row = row0 + quad * 4 + r;
                    if (row < N) out[(size_t)row * 40 + col] = acc[c][r] + b4s[col];
                }
            }
        }
    }
}

extern "C" void kernel_launch(void* const* d_in, const int* in_sizes, int n_in,
                              void* d_out, int out_size, void* d_ws, size_t ws_size,
                              hipStream_t stream)
{
    const float* feat = (const float*)d_in[0];
    const int*   eidx = (const int*)d_in[1];
    const float* W1 = (const float*)d_in[2];
    const float* b1 = (const float*)d_in[3];
    const float* W2 = (const float*)d_in[4];
    const float* b2 = (const float*)d_in[5];
    const float* W3 = (const float*)d_in[6];
    const float* b3 = (const float*)d_in[7];
    const float* W4 = (const float*)d_in[8];
    const float* b4 = (const float*)d_in[9];

    const int N = in_sizes[0] / 64;
    const int E = in_sizes[1] / 2;
    const int* src = eidx;
    const int* dst = eidx + E;

    const int NBUCK = (N + CNODES - 1) / CNODES;   // 196

    unsigned short* featbf = (unsigned short*)d_ws;            // N*64 bf16
    unsigned short* aggF   = featbf + (size_t)N * 64;          // N*64 bf16
    unsigned short* t1     = aggF   + (size_t)N * 64;          // N*64 bf16
    int*   off   = (int*)(t1 + (size_t)N * 64);                // N+1
    int*   ccur  = off + (N + 1);                              // NBUCK
    int*   coff  = ccur + NBUCK;                               // NBUCK+1
    int*   ssrc  = coff + (NBUCK + 1);                         // E
    int*   arena = ssrc + E;                                   // NBUCK*CAP
    float* out   = (float*)d_out;

    hipMemsetAsync(ccur, 0, (size_t)NBUCK * sizeof(int), stream);

    const dim3 blk(256);
    const int gP  = (E + EPB - 1) / EPB;
    const int g64 = (N + 63) / 64;
    const int gC  = (N * 64 / 8 + 255) / 256;
    const int gAg = (int)(((size_t)N * 8 + 255) / 256);

    // CSR build (shared by both aggregation rounds) + feat cast
    cast_k<<<gC, blk, 0, stream>>>(feat, featbf, N * 64 / 8);
    part_a<<<gP, blk, 0, stream>>>(src, dst, ccur, arena, E, NBUCK);
    scanc_k<<<1, blk, 0, stream>>>(ccur, coff, off + N, NBUCK, E);
    csr_fine<<<NBUCK, blk, 0, stream>>>(arena, coff, off, ssrc, N);

    // aggF = mean(featbf[src]) ; t1 = sigmoid(aggF@W1+b1)
    agg_k<<<gAg, blk, 0, stream>>>(featbf, off, ssrc, aggF, N);
    gemmsig_k<<<g64, blk, 0, stream>>>(aggF, off, W1, b1, t1, N);
    // aggF2 = mean(t1[src]) ; out = relu(sigmoid(aggF2@W2+b2)@W3+b3)@W4+b4
    agg_k<<<gAg, blk, 0, stream>>>(t1, off, ssrc, aggF, N);
    ep3_k<<<g64, blk, 0, stream>>>(aggF, off, W2, b2, W3, b3, W4, b4, out, N);
}